// Round 3
// baseline (3297.312 us; speedup 1.0000x reference)
//
#include <hip/hip_runtime.h>

#define N_NODES 24
#define CH 32
#define SPT 4          // samples per thread (amortizes weight reads 4x)
#define BLK 256

// One node per blockIdx.y. Weights staged in LDS once per block; all reads of
// them are wave-uniform broadcast ds_read_b128 (conflict-free). Each thread
// keeps SPT full relu'd input rows in VGPRs (each row = exactly one 128B
// line, loaded with 8 consecutive dwordx4 so the line is fetched once).
// hid is processed in two 16-wide j-halves to keep VGPR < 256.
__global__ __launch_bounds__(BLK, 2) void grouped_pnmlp_kernel(
    const float* __restrict__ h,      // [B][24][32]
    const int*   __restrict__ valid,  // [B][24]
    const float* __restrict__ W1,     // [6][4][32][32]
    const float* __restrict__ b1,     // [6][4][32]
    const float* __restrict__ W2,     // [6][4][32]
    const float* __restrict__ b2,     // [6][4]
    float*       __restrict__ out,    // [B][24]
    int n_samples)
{
    __shared__ float4 sW1[CH * CH / 4];  // [l][jb]: W1[l][4jb..4jb+3]
    __shared__ float4 sB1[CH / 4];
    __shared__ float4 sW2[CH / 4];
    __shared__ float  sB2;

    const int node = blockIdx.y;
    // node -> (group g, slot k) per GROUPING
    int g, k;
    if (node < 12)      { g = node % 3;               k = node / 3;         }
    else if (node < 16) { g = 3;                      k = node - 12;        }
    else                { g = 4 + ((node - 16) & 1);  k = (node - 16) >> 1; }

    int vbase, vstride;
    if (g < 3)       { vbase = g;            vstride = 3; }
    else if (g == 3) { vbase = 12;           vstride = 1; }
    else             { vbase = 16 + (g - 4); vstride = 2; }

    const int gk  = g * 4 + k;
    const int tid = threadIdx.x;

    // stage weights: 256 threads x 1 float4 = 1024 floats of W1
    sW1[tid] = ((const float4*)(W1 + (size_t)gk * CH * CH))[tid];
    if (tid < 8)        sB1[tid]     = ((const float4*)(b1 + (size_t)gk * CH))[tid];
    else if (tid < 16)  sW2[tid - 8] = ((const float4*)(W2 + (size_t)gk * CH))[tid - 8];
    else if (tid == 16) sB2          = b2[gk];
    __syncthreads();

    int bs[SPT];
    const int base = blockIdx.x * (BLK * SPT) + tid;
#pragma unroll
    for (int s = 0; s < SPT; ++s) {
        int b = base + s * BLK;
        bs[s] = (b < n_samples) ? b : (n_samples - 1);  // benign duplicate
    }

    // load + relu all SPT input rows into registers
    float4 xr[SPT][8];
#pragma unroll
    for (int s = 0; s < SPT; ++s) {
        const float4* __restrict__ xp =
            (const float4*)(h + ((size_t)bs[s] * N_NODES + node) * CH);
#pragma unroll
        for (int i = 0; i < 8; ++i) {
            float4 v = xp[i];
            v.x = fmaxf(v.x, 0.f); v.y = fmaxf(v.y, 0.f);
            v.z = fmaxf(v.z, 0.f); v.w = fmaxf(v.w, 0.f);
            xr[s][i] = v;
        }
    }

    float acc[SPT];
#pragma unroll
    for (int s = 0; s < SPT; ++s) acc[s] = sB2;

#pragma unroll
    for (int jh = 0; jh < 2; ++jh) {   // two 16-wide j halves
        float4 hid[SPT][4];
#pragma unroll
        for (int q = 0; q < 4; ++q) {
            float4 bv = sB1[jh * 4 + q];
#pragma unroll
            for (int s = 0; s < SPT; ++s) hid[s][q] = bv;
        }

#pragma unroll
        for (int l = 0; l < CH; ++l) {
#pragma unroll
            for (int q = 0; q < 4; ++q) {
                float4 wv = sW1[l * 8 + jh * 4 + q];   // broadcast b128
#pragma unroll
                for (int s = 0; s < SPT; ++s) {
                    float4 xv = xr[s][l >> 2];
                    const int c = l & 3;               // constant after unroll
                    float xs = (c == 0) ? xv.x : (c == 1) ? xv.y
                             : (c == 2) ? xv.z : xv.w;
                    hid[s][q].x = fmaf(xs, wv.x, hid[s][q].x);
                    hid[s][q].y = fmaf(xs, wv.y, hid[s][q].y);
                    hid[s][q].z = fmaf(xs, wv.z, hid[s][q].z);
                    hid[s][q].w = fmaf(xs, wv.w, hid[s][q].w);
                }
            }
        }

        // layer 2 contribution of this half
#pragma unroll
        for (int q = 0; q < 4; ++q) {
            float4 wv = sW2[jh * 4 + q];
#pragma unroll
            for (int s = 0; s < SPT; ++s) {
                acc[s] = fmaf(fmaxf(hid[s][q].x, 0.f), wv.x, acc[s]);
                acc[s] = fmaf(fmaxf(hid[s][q].y, 0.f), wv.y, acc[s]);
                acc[s] = fmaf(fmaxf(hid[s][q].z, 0.f), wv.z, acc[s]);
                acc[s] = fmaf(fmaxf(hid[s][q].w, 0.f), wv.w, acc[s]);
            }
        }
    }

    // validity mask + store
#pragma unroll
    for (int s = 0; s < SPT; ++s) {
        const int* __restrict__ vrow = valid + (size_t)bs[s] * N_NODES;
        const int vs = vrow[vbase] + vrow[vbase + vstride] +
                       vrow[vbase + 2 * vstride] + vrow[vbase + 3 * vstride];
        out[(size_t)bs[s] * N_NODES + node] = (vs > 0) ? acc[s] : 0.0f;
    }
}

extern "C" void kernel_launch(void* const* d_in, const int* in_sizes, int n_in,
                              void* d_out, int out_size, void* d_ws, size_t ws_size,
                              hipStream_t stream) {
    const float* h     = (const float*)d_in[0];
    const int*   valid = (const int*)d_in[1];
    const float* W1    = (const float*)d_in[2];
    const float* b1    = (const float*)d_in[3];
    const float* W2    = (const float*)d_in[4];
    const float* b2    = (const float*)d_in[5];
    float* out = (float*)d_out;

    const int n_samples = in_sizes[0] / (N_NODES * CH);

    dim3 block(BLK, 1, 1);
    dim3 grid((n_samples + BLK * SPT - 1) / (BLK * SPT), N_NODES, 1);
    grouped_pnmlp_kernel<<<grid, block, 0, stream>>>(h, valid, W1, b1, W2, b2,
                                                     out, n_samples);
}